// Round 11
// baseline (174.422 us; speedup 1.0000x reference)
//
#include <hip/hip_runtime.h>

// Problem: H=W=384, F=K=256. M = 147456 rows.
// out[m,f] = sum_k d[m,k] * y[k,f],  y = x[stations] @ W  (256x256, tiny)
#define FF 256
#define KK 256
#define TILES 4                // 16-row tiles per block (64 rows/block)
#define NBLK 2304              // 2304 * 64 = 147456 rows

typedef __attribute__((ext_vector_type(8))) short bf16x8;   // 8 bf16 (4 VGPR)
typedef __attribute__((ext_vector_type(4))) float f32x4;    // MFMA C/D frag

// float -> bf16 bits, round-to-nearest-even
__device__ inline short f2bf(float x) {
    unsigned u = __float_as_uint(x);
    unsigned r = u + 0x7FFFu + ((u >> 16) & 1u);
    return (short)(r >> 16);
}

// Kernel 1: y[k][f] = sum_j x[sx[k],sy[k],j] * W[j][f], stored bf16 in
// FRAGMENT ORDER so kernel-2 B loads are lane-contiguous 16B/lane:
//   idx(k,f) = ((f>>4)*8 + (k>>5))*512 + (((k>>3)&3)*16 + (f&15))*8 + (k&7)
__global__ __launch_bounds__(256) void station_kernel(
        const float* __restrict__ x, const float* __restrict__ W,
        const int* __restrict__ sx, const int* __restrict__ sy,
        short* __restrict__ yp) {
    __shared__ float xrow[FF];
    const int k = blockIdx.x;
    const int f = threadIdx.x;
    const long base = ((long)sx[k] * 384 + (long)sy[k]) * FF;
    xrow[f] = x[base + f];
    __syncthreads();
    float acc = 0.f;
    #pragma unroll 8
    for (int j = 0; j < FF; ++j)
        acc += xrow[j] * W[j * FF + f];   // coalesced across f
    const int idx = ((f >> 4) * 8 + (k >> 5)) * 512
                  + (((k >> 3) & 3) * 16 + (f & 15)) * 8 + (k & 7);
    yp[idx] = f2bf(acc);
}

// issue half h (kf = h*4 .. h*4+3) of the tile at row-base dp into pv[8]
__device__ inline void issue_half(float4* pv, const float* dp, int h) {
    #pragma unroll
    for (int j = 0; j < 4; ++j) {
        const int kf = h * 4 + j;
        pv[2 * j]     = *(const float4*)(dp + kf * 32);
        pv[2 * j + 1] = *(const float4*)(dp + kf * 32 + 4);
    }
}

// Kernel 2: barrier-free, LDS-free. 512-thread blocks = 8 independent waves
// covering the SAME 64 rows (L1/L2 dedupe on one CU), each owning 32 cols
// with B-fragments asm-pinned resident. Rolling half-tile register pipeline:
// ~8-16 loads always in flight per wave; compiler waitcnts land at vmcnt(8).
__global__ __launch_bounds__(512, 3) void gemm_kernel(
        const float* __restrict__ d, const short* __restrict__ yp,
        float* __restrict__ out) {
    const int t    = threadIdx.x;
    const int lane = t & 63;
    const int wid  = t >> 6;          // 0..7: 32-col slice
    const int l15  = lane & 15;
    const int lg   = lane >> 4;       // 0..3: k-subgroup

    const long mblk = (long)blockIdx.x * (16 * TILES);

    // ---- B fragments: 16 x 16B/lane coalesced loads, pinned resident ----
    bf16x8 bfrag[8][2];
    #pragma unroll
    for (int kf = 0; kf < 8; ++kf)
        #pragma unroll
        for (int nf = 0; nf < 2; ++nf) {
            const int g = wid * 2 + nf;              // 16-col group 0..15
            bfrag[kf][nf] = *(const bf16x8*)(yp + ((g * 8 + kf) << 9) + (lane << 3));
        }
    asm volatile("" :
        "+v"(bfrag[0][0]), "+v"(bfrag[0][1]), "+v"(bfrag[1][0]), "+v"(bfrag[1][1]),
        "+v"(bfrag[2][0]), "+v"(bfrag[2][1]), "+v"(bfrag[3][0]), "+v"(bfrag[3][1]),
        "+v"(bfrag[4][0]), "+v"(bfrag[4][1]), "+v"(bfrag[5][0]), "+v"(bfrag[5][1]),
        "+v"(bfrag[6][0]), "+v"(bfrag[6][1]), "+v"(bfrag[7][0]), "+v"(bfrag[7][1]));

    // Per-lane A row base: lane reads d[(m0+l15)*KK + lg*8 + kf*32 .. +7]
    // (one wave instr = 16 rows x 128B contiguous)
    const float* dp = d + (mblk + l15) * KK + lg * 8;

    float4 pva[8], pvb[8];
    // prologue: fill both half-buffers for tile 0 (16 loads in flight)
    issue_half(pva, dp, 0);
    issue_half(pvb, dp, 1);

    for (int tt = 0; tt < TILES; ++tt) {
        const long m0 = mblk + (long)tt * 16;
        const float* dpn = dp + (tt + 1) * 16 * KK;  // next tile's row base

        f32x4 acc[2];
        #pragma unroll
        for (int nf = 0; nf < 2; ++nf)
            #pragma unroll
            for (int q = 0; q < 4; ++q) acc[nf][q] = 0.f;

        // ---- compute half 0 (kf 0..3) from pva ----
        #pragma unroll
        for (int j = 0; j < 4; ++j) {
            const float4 lo = pva[2 * j];
            const float4 hi = pva[2 * j + 1];
            bf16x8 a;
            a[0] = f2bf(lo.x); a[1] = f2bf(lo.y);
            a[2] = f2bf(lo.z); a[3] = f2bf(lo.w);
            a[4] = f2bf(hi.x); a[5] = f2bf(hi.y);
            a[6] = f2bf(hi.z); a[7] = f2bf(hi.w);
            #pragma unroll
            for (int nf = 0; nf < 2; ++nf)
                acc[nf] = __builtin_amdgcn_mfma_f32_16x16x32_bf16(
                              a, bfrag[j][nf], acc[nf], 0, 0, 0);
        }
        // refill pva with next tile's half 0 (keeps ~8-16 loads in flight)
        if (tt + 1 < TILES) issue_half(pva, dpn, 0);

        // ---- compute half 1 (kf 4..7) from pvb ----
        #pragma unroll
        for (int j = 0; j < 4; ++j) {
            const float4 lo = pvb[2 * j];
            const float4 hi = pvb[2 * j + 1];
            bf16x8 a;
            a[0] = f2bf(lo.x); a[1] = f2bf(lo.y);
            a[2] = f2bf(lo.z); a[3] = f2bf(lo.w);
            a[4] = f2bf(hi.x); a[5] = f2bf(hi.y);
            a[6] = f2bf(hi.z); a[7] = f2bf(hi.w);
            #pragma unroll
            for (int nf = 0; nf < 2; ++nf)
                acc[nf] = __builtin_amdgcn_mfma_f32_16x16x32_bf16(
                              a, bfrag[4 + j][nf], acc[nf], 0, 0, 0);
        }
        if (tt + 1 < TILES) issue_half(pvb, dpn, 1);

        // ---- store C: row = lg*4 + q, col = wid*32 + nf*16 + l15 ----
        float* ob = out + m0 * FF + wid * 32;
        #pragma unroll
        for (int nf = 0; nf < 2; ++nf)
            #pragma unroll
            for (int q = 0; q < 4; ++q)
                ob[(long)(lg * 4 + q) * FF + nf * 16 + l15] = acc[nf][q];
    }
}

extern "C" void kernel_launch(void* const* d_in, const int* in_sizes, int n_in,
                              void* d_out, int out_size, void* d_ws, size_t ws_size,
                              hipStream_t stream) {
    const float* x  = (const float*)d_in[0];
    const float* d  = (const float*)d_in[1];
    const float* W  = (const float*)d_in[2];
    const int*   sx = (const int*)d_in[3];
    const int*   sy = (const int*)d_in[4];
    float* out = (float*)d_out;
    short* yp  = (short*)d_ws;   // 256*256 bf16 = 128 KB packed fragment buffer

    station_kernel<<<dim3(KK), dim3(FF), 0, stream>>>(x, W, sx, sy, yp);
    gemm_kernel<<<dim3(NBLK), dim3(512), 0, stream>>>(d, yp, out);
}

// Round 12
// 137.438 us; speedup vs baseline: 1.2691x; 1.2691x over previous
//
#include <hip/hip_runtime.h>

// Problem: H=W=384, F=K=256. M = 147456 rows.
// out[m,f] = sum_k d[m,k] * y[k,f],  y = x[stations] @ W  (256x256, tiny)
#define FF 256
#define KK 256
#define NBLK 36864             // 9216 row-tiles x 4 col-quarters

typedef __attribute__((ext_vector_type(8))) short bf16x8;   // 8 bf16 (4 VGPR)
typedef __attribute__((ext_vector_type(4))) float f32x4;    // MFMA C/D frag
typedef __attribute__((ext_vector_type(4))) short short4v;  // 4 bf16 (8 B)

// float -> bf16 bits, round-to-nearest-even
__device__ inline short f2bf(float x) {
    unsigned u = __float_as_uint(x);
    unsigned r = u + 0x7FFFu + ((u >> 16) & 1u);
    return (short)(r >> 16);
}

// Kernel 1: y[k][f] = sum_j x[sx[k],sy[k],j] * W[j][f], stored bf16 in
// FRAGMENT ORDER so kernel-2 B loads are lane-contiguous 16B/lane:
//   idx(k,f) = ((f>>4)*8 + (k>>5))*512 + (((k>>3)&3)*16 + (f&15))*8 + (k&7)
__global__ __launch_bounds__(256) void station_kernel(
        const float* __restrict__ x, const float* __restrict__ W,
        const int* __restrict__ sx, const int* __restrict__ sy,
        short* __restrict__ yp) {
    __shared__ float xrow[FF];
    const int k = blockIdx.x;
    const int f = threadIdx.x;
    const long base = ((long)sx[k] * 384 + (long)sy[k]) * FF;
    xrow[f] = x[base + f];
    __syncthreads();
    float acc = 0.f;
    #pragma unroll 8
    for (int j = 0; j < FF; ++j)
        acc += xrow[j] * W[j * FF + f];   // coalesced across f
    const int idx = ((f >> 4) * 8 + (k >> 5)) * 512
                  + (((k >> 3) & 3) * 16 + (f & 15)) * 8 + (k & 7);
    yp[idx] = f2bf(acc);
}

// Kernel 2: single-shot tiny blocks — no loop, no double buffer, ONE barrier.
// Block = 256 thr (4 waves) = 16 rows x 64 cols; wave owns 16 cols
// (bfrag[8][1], 32 regs). ~6 waves/SIMD occupancy; the grid (36864 blocks)
// is the pipeline: block lifecycles overlap freely on each CU.
__global__ __launch_bounds__(256) void gemm_kernel(
        const float* __restrict__ d, const short* __restrict__ yp,
        float* __restrict__ out) {
    __shared__ __align__(16) short lds[16 * KK];   // 8 KB bf16, swizzled
    const int t    = threadIdx.x;
    const int lane = t & 63;
    const int wid  = t >> 6;          // 0..3: 16-col slice within quarter
    const int l15  = lane & 15;
    const int lg   = lane >> 4;       // 0..3: k-subgroup

    // Bijective XCD swizzle (NBLK % 8 == 0): the 4 col-quarters of a row-tile
    // get consecutive work ids -> same XCD -> d rows fetched once per XCD.
    const int work    = (blockIdx.x & 7) * (NBLK / 8) + (blockIdx.x >> 3);
    const int quarter = work & 3;               // 64-col quarter
    const long m0     = (long)(work >> 2) * 16; // row-tile base

    // ---- B fragments: 8 x 16B/lane coalesced loads (L2/L3-resident) ----
    bf16x8 bfrag[8];
    const int g = quarter * 4 + wid;            // 16-col group 0..15
    #pragma unroll
    for (int kf = 0; kf < 8; ++kf)
        bfrag[kf] = *(const bf16x8*)(yp + ((g * 8 + kf) << 9) + (lane << 3));
    asm volatile("" :
        "+v"(bfrag[0]), "+v"(bfrag[1]), "+v"(bfrag[2]), "+v"(bfrag[3]),
        "+v"(bfrag[4]), "+v"(bfrag[5]), "+v"(bfrag[6]), "+v"(bfrag[7]));

    // ---- stage A: 16 rows x 256 f32 -> bf16 LDS (coalesced, swizzled) ----
    char* lb = (char*)lds;
    {
        const float* dp = d + m0 * KK;
        float4 pv[4];
        #pragma unroll
        for (int p = 0; p < 4; ++p)
            pv[p] = *(const float4*)(dp + (p * 256 + t) * 4);
        #pragma unroll
        for (int p = 0; p < 4; ++p) {
            const int row = p * 4 + wid;          // 4 passes x 4 rows
            int byte = row * 512 + (t & 63) * 8;
            byte ^= (row & 7) << 4;               // bank swizzle (G4)
            short4v b;
            b.x = f2bf(pv[p].x); b.y = f2bf(pv[p].y);
            b.z = f2bf(pv[p].z); b.w = f2bf(pv[p].w);
            *(short4v*)(lb + byte) = b;
        }
    }
    __syncthreads();

    // ---- compute: 8 x (ds_read_b128 + MFMA), B resident ----
    f32x4 acc;
    #pragma unroll
    for (int q = 0; q < 4; ++q) acc[q] = 0.f;

    #pragma unroll
    for (int kf = 0; kf < 8; ++kf) {
        const int cb = kf * 64 + lg * 16;
        const int xo = (l15 & 7) << 4;
        bf16x8 a0 = *(const bf16x8*)(lb + ((l15 * 512 + cb) ^ xo));
        acc = __builtin_amdgcn_mfma_f32_16x16x32_bf16(a0, bfrag[kf], acc, 0, 0, 0);
    }

    // ---- store C: row = lg*4 + q, col = quarter*64 + wid*16 + l15 ----
    float* ob = out + m0 * FF + quarter * 64 + wid * 16;
    #pragma unroll
    for (int q = 0; q < 4; ++q)
        ob[(long)(lg * 4 + q) * FF + l15] = acc[q];
}

extern "C" void kernel_launch(void* const* d_in, const int* in_sizes, int n_in,
                              void* d_out, int out_size, void* d_ws, size_t ws_size,
                              hipStream_t stream) {
    const float* x  = (const float*)d_in[0];
    const float* d  = (const float*)d_in[1];
    const float* W  = (const float*)d_in[2];
    const int*   sx = (const int*)d_in[3];
    const int*   sy = (const int*)d_in[4];
    float* out = (float*)d_out;
    short* yp  = (short*)d_ws;   // 256*256 bf16 = 128 KB packed fragment buffer

    station_kernel<<<dim3(KK), dim3(FF), 0, stream>>>(x, W, sx, sy, yp);
    gemm_kernel<<<dim3(NBLK), dim3(256), 0, stream>>>(d, yp, out);
}

// Round 13
// 77.590 us; speedup vs baseline: 2.2480x; 1.7713x over previous
//
#include <hip/hip_runtime.h>

// Problem: H=W=384, F=K=256. M = 147456 rows.
// out[m,f] = sum_k d[m,k] * y[k,f],  y = x[stations] @ W  (256x256, tiny)
#define FF 256
#define KK 256
#define RR 16                  // rows per stripe
#define STRIPES 4              // stripes per block -> 64 rows/block
#define NBLK 4608              // (147456/64 rowgroups) * 2 col-halves
#define HALFC 128              // cols per block (half of FF)

typedef __attribute__((ext_vector_type(8))) short bf16x8;   // 8 bf16 (4 VGPR)
typedef __attribute__((ext_vector_type(4))) float f32x4;    // MFMA C/D frag
typedef __attribute__((ext_vector_type(4))) short short4v;  // 4 bf16 (8 B)

// float -> bf16 bits, round-to-nearest-even
__device__ inline short f2bf(float x) {
    unsigned u = __float_as_uint(x);
    unsigned r = u + 0x7FFFu + ((u >> 16) & 1u);
    return (short)(r >> 16);
}

// Kernel 1: y[k][f] = sum_j x[sx[k],sy[k],j] * W[j][f], stored bf16 in
// FRAGMENT ORDER so kernel-2 B loads are lane-contiguous 16B/lane:
//   idx(k,f) = ((f>>4)*8 + (k>>5))*512 + (((k>>3)&3)*16 + (f&15))*8 + (k&7)
__global__ __launch_bounds__(256) void station_kernel(
        const float* __restrict__ x, const float* __restrict__ W,
        const int* __restrict__ sx, const int* __restrict__ sy,
        short* __restrict__ yp) {
    __shared__ float xrow[FF];
    const int k = blockIdx.x;
    const int f = threadIdx.x;
    const long base = ((long)sx[k] * 384 + (long)sy[k]) * FF;
    xrow[f] = x[base + f];
    __syncthreads();
    float acc = 0.f;
    #pragma unroll 8
    for (int j = 0; j < FF; ++j)
        acc += xrow[j] * W[j * FF + f];   // coalesced across f
    const int idx = ((f >> 4) * 8 + (k >> 5)) * 512
                  + (((k >> 3) & 3) * 16 + (f & 15)) * 8 + (k & 7);
    yp[idx] = f2bf(acc);
}

// Kernel 2: identical to round 9 EXCEPT the C-store goes through an 8 KB
// LDS transpose tile so global writes are full-line contiguous (512 B-chunk
// per wave-instruction) instead of scattered 64 B row-segments.
__global__ __launch_bounds__(256, 4) void gemm_kernel(
        const float* __restrict__ d, const short* __restrict__ yp,
        float* __restrict__ out) {
    __shared__ __align__(16) short ldsA[2][RR * KK];   // 2 x 8 KB A, swizzled
    __shared__ __align__(16) float ldsC[RR * HALFC];   // 8 KB C staging
    const int t    = threadIdx.x;
    const int lane = t & 63;
    const int wid  = t >> 6;          // 0..3: 32-col slice within the half
    const int l15  = lane & 15;
    const int lg   = lane >> 4;       // 0..3: k-subgroup

    // Bijective XCD swizzle (NBLK % 8 == 0): row-sharing col-half pairs co-XCD.
    const int work = (blockIdx.x & 7) * (NBLK / 8) + (blockIdx.x >> 3);
    const int half = work & 1;                  // col half: 0..1 (128 cols)
    const long mblk = (long)(work >> 1) * (RR * STRIPES);

    char* lb0 = (char*)ldsA[0];
    char* lb1 = (char*)ldsA[1];

    // ---- B fragments: 16 x 16B/lane coalesced loads, once per block ----
    bf16x8 bfrag[8][2];
    #pragma unroll
    for (int kf = 0; kf < 8; ++kf)
        #pragma unroll
        for (int nf = 0; nf < 2; ++nf) {
            const int g = half * 8 + wid * 2 + nf;   // 16-col group 0..15
            bfrag[kf][nf] = *(const bf16x8*)(yp + ((g * 8 + kf) << 9) + (lane << 3));
        }
    // Anti-remat value barrier: keep them register/AGPR-resident.
    asm volatile("" :
        "+v"(bfrag[0][0]), "+v"(bfrag[0][1]), "+v"(bfrag[1][0]), "+v"(bfrag[1][1]),
        "+v"(bfrag[2][0]), "+v"(bfrag[2][1]), "+v"(bfrag[3][0]), "+v"(bfrag[3][1]),
        "+v"(bfrag[4][0]), "+v"(bfrag[4][1]), "+v"(bfrag[5][0]), "+v"(bfrag[5][1]),
        "+v"(bfrag[6][0]), "+v"(bfrag[6][1]), "+v"(bfrag[7][0]), "+v"(bfrag[7][1]));

    // staging geometry: pass p covers rows p*4 + (t>>6), lane writes 8B at
    // col-byte 8*(t&63). 4 passes x 256 thr x 4 floats = 4096 = 16 rows.
    const int srow0 = t >> 6;
    const int scol  = (t & 63) * 8;

    // ---- prologue: load + stage stripe 0 into buf0 ----
    float4 pv[4];
    {
        const float* dp = d + mblk * KK;
        #pragma unroll
        for (int p = 0; p < 4; ++p)
            pv[p] = *(const float4*)(dp + (p * 256 + t) * 4);
        #pragma unroll
        for (int p = 0; p < 4; ++p) {
            const int row = p * 4 + srow0;
            int byte = row * 512 + scol;
            byte ^= (row & 7) << 4;               // bank swizzle (G4)
            short4v b;
            b.x = f2bf(pv[p].x); b.y = f2bf(pv[p].y);
            b.z = f2bf(pv[p].z); b.w = f2bf(pv[p].w);
            *(short4v*)(lb0 + byte) = b;
        }
    }
    __syncthreads();

    for (int s = 0; s < STRIPES; ++s) {
        const long m0 = mblk + (long)s * RR;
        char* cur = (s & 1) ? lb1 : lb0;
        char* nxt = (s & 1) ? lb0 : lb1;

        // (1) issue next stripe's global loads — vmcnt waits land at convert
        if (s + 1 < STRIPES) {
            const float* dp = d + (m0 + RR) * KK;
            #pragma unroll
            for (int p = 0; p < 4; ++p)
                pv[p] = *(const float4*)(dp + (p * 256 + t) * 4);
        }

        // (2) compute current stripe: A from LDS, B resident
        f32x4 acc[2];
        #pragma unroll
        for (int nf = 0; nf < 2; ++nf)
            #pragma unroll
            for (int q = 0; q < 4; ++q) acc[nf][q] = 0.f;

        #pragma unroll
        for (int kf = 0; kf < 8; ++kf) {
            const int cb = kf * 64 + lg * 16;
            const int xo = (l15 & 7) << 4;
            bf16x8 a0 = *(const bf16x8*)(cur + ((l15 * 512 + cb) ^ xo));
            #pragma unroll
            for (int nf = 0; nf < 2; ++nf)
                acc[nf] = __builtin_amdgcn_mfma_f32_16x16x32_bf16(
                              a0, bfrag[kf][nf], acc[nf], 0, 0, 0);
        }

        // (3) C fragments -> LDS tile (scatter, cheap), then barrier
        #pragma unroll
        for (int nf = 0; nf < 2; ++nf)
            #pragma unroll
            for (int q = 0; q < 4; ++q)
                ldsC[(lg * 4 + q) * HALFC + wid * 32 + nf * 16 + l15]
                    = acc[nf][q];
        __syncthreads();

        // (4) stream C tile out LINEARLY: each pass = 1024 consecutive floats;
        // per wave-instruction: 2 full rows x 512 B contiguous (4 cache lines).
        #pragma unroll
        for (int p = 0; p < 2; ++p) {
            const int e = p * 1024 + t * 4;          // element index in tile
            const float4 v = *(const float4*)(ldsC + e);
            *(float4*)(out + (m0 + (e >> 7)) * FF + half * HALFC + (e & 127)) = v;
        }

        // (5) convert + LDS-write pending A stripe into nxt
        if (s + 1 < STRIPES) {
            #pragma unroll
            for (int p = 0; p < 4; ++p) {
                const int row = p * 4 + srow0;
                int byte = row * 512 + scol;
                byte ^= (row & 7) << 4;
                short4v b;
                b.x = f2bf(pv[p].x); b.y = f2bf(pv[p].y);
                b.z = f2bf(pv[p].z); b.w = f2bf(pv[p].w);
                *(short4v*)(nxt + byte) = b;
            }
        }

        // (6) close the stripe: C tile free for reuse, A nxt buffer ready
        __syncthreads();
    }
}

extern "C" void kernel_launch(void* const* d_in, const int* in_sizes, int n_in,
                              void* d_out, int out_size, void* d_ws, size_t ws_size,
                              hipStream_t stream) {
    const float* x  = (const float*)d_in[0];
    const float* d  = (const float*)d_in[1];
    const float* W  = (const float*)d_in[2];
    const int*   sx = (const int*)d_in[3];
    const int*   sy = (const int*)d_in[4];
    float* out = (float*)d_out;
    short* yp  = (short*)d_ws;   // 256*256 bf16 = 128 KB packed fragment buffer

    station_kernel<<<dim3(KK), dim3(FF), 0, stream>>>(x, W, sx, sy, yp);
    gemm_kernel<<<dim3(NBLK), dim3(256), 0, stream>>>(d, yp, out);
}